// Round 1
// baseline (560.805 us; speedup 1.0000x reference)
//
#include <hip/hip_runtime.h>
#include <hip/hip_bf16.h>

#define H 512
#define B 64
#define S 2048

#define BM 128
#define BN 128
#define BK 32

typedef __bf16 bf16x8 __attribute__((ext_vector_type(8)));
typedef float f32x4 __attribute__((ext_vector_type(4)));

// pack two fp32 -> two bf16 (RNE) in one uint (low = x)
__device__ __forceinline__ unsigned cvt2(float x, float y) {
    union { __hip_bfloat162 h; unsigned u; } cv;
    cv.h = __float22bfloat162_rn(make_float2(x, y));
    return cv.u;
}

__device__ __forceinline__ float fast_tanh(float x) {
    float e = __expf(2.0f * x);                  // v_exp_f32 path
    float r = __builtin_amdgcn_rcpf(e + 1.0f);   // approx rcp, ~1ulp
    return 1.0f - 2.0f * r;                      // exact at +/-inf limits
}

// u[b,k] = U_b[k] + W_b[k] + sum_h U_w[k,h] * hid[b,h]
__global__ void u_kernel(const float* __restrict__ hid, const float* __restrict__ Uw,
                         const float* __restrict__ Ub, const float* __restrict__ Wb,
                         float* __restrict__ u) {
    __shared__ float sh[H];
    int b = blockIdx.x;
    int t = threadIdx.x;              // 512 threads
    sh[t] = hid[b * H + t];
    __syncthreads();
    const float4* row = (const float4*)(Uw + (size_t)t * H);
    float acc = 0.f;
    #pragma unroll 4
    for (int i = 0; i < H / 4; ++i) {
        float4 w4 = row[i];
        acc += w4.x * sh[4 * i] + w4.y * sh[4 * i + 1] + w4.z * sh[4 * i + 2] + w4.w * sh[4 * i + 3];
    }
    u[b * H + t] = acc + Ub[t] + Wb[t];
}

// Fused: C[s,k] = sum_h enc[b,s,h]*W[k,h]; energy[b,s] += sum_k v[k]*tanh(u[b,k]+C[s,k])
__global__ __launch_bounds__(256) void energy_kernel(
        const float* __restrict__ enc, const float* __restrict__ Ww,
        const float* __restrict__ Vw, const float* __restrict__ u,
        float* __restrict__ energy) {
    const int kt = blockIdx.x;        // 0..3   (k-tile, fastest -> A-tile L3 reuse)
    const int st = blockIdx.y;        // 0..15  (s-tile)
    const int b  = blockIdx.z;        // 0..63
    const int k0 = kt * BN;
    const int s0 = st * BM;
    const int tid  = threadIdx.x;
    const int wave = tid >> 6;
    const int lane = tid & 63;
    const int wr = wave >> 1, wc = wave & 1;
    const int quad = lane >> 4, c = lane & 15;

    __shared__ unsigned short As[BM][BK];   // enc tile (bf16 bits), 8KB
    __shared__ unsigned short Bs[BN][BK];   // W rows   (bf16 bits), 8KB
    __shared__ float uS[BN], vS[BN];

    if (tid < BN) { uS[tid] = u[b * H + k0 + tid]; vS[tid] = Vw[k0 + tid]; }

    f32x4 acc[4][4] = {};

    const float* Abase = enc + ((size_t)(b * S + s0)) * H;
    const float* Bbase = Ww + (size_t)k0 * H;

    for (int kk = 0; kk < H / BK; ++kk) {
        const int h0 = kk * BK;
        __syncthreads();   // protect LDS from previous iteration's readers (and uS on kk==0)
        #pragma unroll
        for (int i = 0; i < 4; ++i) {
            int f   = tid + i * 256;          // 0..1023 float4-chunks
            int row = f >> 3;                  // 0..127
            int c4  = (f & 7) * 4;             // 0,4,..,28
            float4 a4 = *(const float4*)(Abase + (size_t)row * H + h0 + c4);
            float4 b4 = *(const float4*)(Bbase + (size_t)row * H + h0 + c4);
            uint2 ap, bp;
            ap.x = cvt2(a4.x, a4.y); ap.y = cvt2(a4.z, a4.w);
            bp.x = cvt2(b4.x, b4.y); bp.y = cvt2(b4.z, b4.w);
            *(uint2*)&As[row][c4] = ap;
            *(uint2*)&Bs[row][c4] = bp;
        }
        __syncthreads();
        bf16x8 af[4], bfr[4];
        #pragma unroll
        for (int i = 0; i < 4; ++i) af[i]  = *(const bf16x8*)&As[wr * 64 + i * 16 + c][quad * 8];
        #pragma unroll
        for (int j = 0; j < 4; ++j) bfr[j] = *(const bf16x8*)&Bs[wc * 64 + j * 16 + c][quad * 8];
        #pragma unroll
        for (int i = 0; i < 4; ++i)
            #pragma unroll
            for (int j = 0; j < 4; ++j)
                acc[i][j] = __builtin_amdgcn_mfma_f32_16x16x32_bf16(af[i], bfr[j], acc[i][j], 0, 0, 0);
    }

    // epilogue: per C row, sum_k v[k]*tanh(u[k]+C[s,k]) over this block's 128 k's
    float* erow = energy + b * S + s0;
    #pragma unroll
    for (int i = 0; i < 4; ++i) {
        #pragma unroll
        for (int r = 0; r < 4; ++r) {
            float esum = 0.f;
            #pragma unroll
            for (int j = 0; j < 4; ++j) {
                int col = wc * 64 + j * 16 + c;
                esum += vS[col] * fast_tanh(uS[col] + acc[i][j][r]);
            }
            esum += __shfl_xor(esum, 1, 64);
            esum += __shfl_xor(esum, 2, 64);
            esum += __shfl_xor(esum, 4, 64);
            esum += __shfl_xor(esum, 8, 64);
            if (c == 0) atomicAdd(&erow[wr * 64 + i * 16 + quad * 4 + r], esum);
        }
    }
}

__global__ void softmax_kernel(const float* __restrict__ energy, float* __restrict__ attn) {
    int b = blockIdx.x;
    int t = threadIdx.x;              // 256
    const float* e = energy + b * S;
    float v[8];
    float m = -1e30f;
    #pragma unroll
    for (int i = 0; i < 8; ++i) { v[i] = e[t + i * 256]; m = fmaxf(m, v[i]); }
    #pragma unroll
    for (int off = 1; off < 64; off <<= 1) m = fmaxf(m, __shfl_xor(m, off, 64));
    __shared__ float redm[4], reds[4];
    if ((t & 63) == 0) redm[t >> 6] = m;
    __syncthreads();
    m = fmaxf(fmaxf(redm[0], redm[1]), fmaxf(redm[2], redm[3]));
    float s = 0.f;
    #pragma unroll
    for (int i = 0; i < 8; ++i) { v[i] = __expf(v[i] - m); s += v[i]; }
    #pragma unroll
    for (int off = 1; off < 64; off <<= 1) s += __shfl_xor(s, off, 64);
    if ((t & 63) == 0) reds[t >> 6] = s;
    __syncthreads();
    float inv = 1.0f / (reds[0] + reds[1] + reds[2] + reds[3]);
    #pragma unroll
    for (int i = 0; i < 8; ++i) attn[b * S + t + i * 256] = v[i] * inv;
}

#define CCHUNK 256
__global__ void context_kernel(const float* __restrict__ enc, const float* __restrict__ attn,
                               float* __restrict__ ctx) {
    int b  = blockIdx.x >> 3;
    int ch = blockIdx.x & 7;
    int t  = threadIdx.x;             // 256
    __shared__ float aS[CCHUNK];
    aS[t] = attn[b * S + ch * CCHUNK + t];
    __syncthreads();
    const float* ebase = enc + ((size_t)(b * S + ch * CCHUNK)) * H + t;
    float c0 = 0.f, c1 = 0.f;
    #pragma unroll 4
    for (int s = 0; s < CCHUNK; ++s) {
        float a = aS[s];
        c0 += a * ebase[(size_t)s * H];
        c1 += a * ebase[(size_t)s * H + 256];
    }
    atomicAdd(&ctx[b * H + t], c0);
    atomicAdd(&ctx[b * H + t + 256], c1);
}

extern "C" void kernel_launch(void* const* d_in, const int* in_sizes, int n_in,
                              void* d_out, int out_size, void* d_ws, size_t ws_size,
                              hipStream_t stream) {
    (void)in_sizes; (void)n_in; (void)out_size; (void)ws_size;
    const float* hid = (const float*)d_in[0];
    const float* enc = (const float*)d_in[1];
    const float* Uw  = (const float*)d_in[2];
    const float* Ub  = (const float*)d_in[3];
    const float* Ww  = (const float*)d_in[4];
    const float* Wb  = (const float*)d_in[5];
    const float* Vw  = (const float*)d_in[6];
    // V_b (d_in[7]) intentionally unused: softmax is shift-invariant, energy not an output.

    float* out_ctx  = (float*)d_out;          // 64*512
    float* out_attn = out_ctx + B * H;        // 64*2048
    float* energy   = (float*)d_ws;           // 64*2048 fp32
    float* u        = energy + B * S;         // 64*512 fp32

    hipMemsetAsync(d_out, 0, (size_t)B * H * sizeof(float), stream);   // context accum target
    hipMemsetAsync(energy, 0, (size_t)B * S * sizeof(float), stream);  // energy accum target

    u_kernel<<<B, H, 0, stream>>>(hid, Uw, Ub, Wb, u);
    energy_kernel<<<dim3(4, 16, B), 256, 0, stream>>>(enc, Ww, Vw, u, energy);
    softmax_kernel<<<B, 256, 0, stream>>>(energy, out_attn);
    context_kernel<<<B * 8, 256, 0, stream>>>(enc, out_attn, out_ctx);
}

// Round 2
// 549.464 us; speedup vs baseline: 1.0206x; 1.0206x over previous
//
#include <hip/hip_runtime.h>
#include <hip/hip_bf16.h>

#define H 512
#define B 64
#define S 2048

#define BM 128
#define BN 128
#define BK 32

typedef __bf16 bf16x8 __attribute__((ext_vector_type(8)));
typedef float f32x4 __attribute__((ext_vector_type(4)));

// pack two fp32 -> two bf16 (RNE) in one uint (low = x)
__device__ __forceinline__ unsigned cvt2(float x, float y) {
    union { __hip_bfloat162 h; unsigned u; } cv;
    cv.h = __float22bfloat162_rn(make_float2(x, y));
    return cv.u;
}

__device__ __forceinline__ float fast_tanh(float x) {
    float e = __expf(2.0f * x);
    float r = __builtin_amdgcn_rcpf(e + 1.0f);
    return 1.0f - 2.0f * r;
}

// u[b,k] = U_b[k] + W_b[k] + sum_h U_w[k,h] * hid[b,h]
// wave-per-row: lane reads 32B contiguous of the row (coalesced), shuffle-reduce.
__global__ __launch_bounds__(256) void u_kernel(
        const float* __restrict__ hid, const float* __restrict__ Uw,
        const float* __restrict__ Ub, const float* __restrict__ Wb,
        float* __restrict__ u) {
    const int b = blockIdx.y;
    const int k = blockIdx.x * 4 + (threadIdx.x >> 6);   // 4 waves -> 4 rows
    const int lane = threadIdx.x & 63;
    const float4* wrow = (const float4*)(Uw + (size_t)k * H);
    const float4* hrow = (const float4*)(hid + (size_t)b * H);
    float4 w0 = wrow[lane * 2], w1 = wrow[lane * 2 + 1];
    float4 h0 = hrow[lane * 2], h1 = hrow[lane * 2 + 1];
    float acc = w0.x * h0.x + w0.y * h0.y + w0.z * h0.z + w0.w * h0.w
              + w1.x * h1.x + w1.y * h1.y + w1.z * h1.z + w1.w * h1.w;
    #pragma unroll
    for (int off = 1; off < 64; off <<= 1) acc += __shfl_xor(acc, off, 64);
    if (lane == 0) u[b * H + k] = acc + Ub[k] + Wb[k];
}

// Fused: for each s-tile of 128 rows of one batch b, loop all 4 k-tiles:
//   C[s,k] = sum_h enc[b,s,h]*W[k,h] (bf16 MFMA), accumulate
//   esum[s] += sum_k v[k]*tanh(u[b,k]+C[s,k]) in registers across k-tiles,
// then block-reduce and write energy[b,s] directly (no atomics).
__global__ __launch_bounds__(256) void energy_kernel(
        const float* __restrict__ enc, const float* __restrict__ Ww,
        const float* __restrict__ Vw, const float* __restrict__ u,
        float* __restrict__ energy) {
    const int st = blockIdx.x;        // 0..15
    const int b  = blockIdx.y;        // 0..63
    const int s0 = st * BM;
    const int tid  = threadIdx.x;
    const int wave = tid >> 6;
    const int lane = tid & 63;
    const int wr = wave >> 1, wc = wave & 1;
    const int quad = lane >> 4, c = lane & 15;

    __shared__ unsigned short As[BM][BK];   // 8KB  (bf16 bits)
    __shared__ unsigned short Bs[BN][BK];   // 8KB
    __shared__ float uS[H], vS[H];          // 4KB
    __shared__ float red[BM];               // cross-wave energy reduce

    #pragma unroll
    for (int i = tid; i < H; i += 256) { uS[i] = u[b * H + i]; vS[i] = Vw[i]; }

    // per-thread staging bases: fixed (row,col) per i-chunk
    const int srow = tid >> 3;              // 0..31  (+ i*32)
    const int sc4  = (tid & 7) * 4;         // float offset in 32-col chunk
    const float* pA = enc + ((size_t)(b * S + s0) + srow) * H + sc4;

    float esum[4][4] = {};                  // [i][r] partial energies

    for (int kt = 0; kt < 4; ++kt) {
        const float* pB = Ww + ((size_t)(kt * BN) + srow) * H + sc4;
        f32x4 acc[4][4] = {};

        float4 pa[4], pb[4];
        #pragma unroll
        for (int i = 0; i < 4; ++i) {
            pa[i] = *(const float4*)(pA + (size_t)i * 32 * H);
            pb[i] = *(const float4*)(pB + (size_t)i * 32 * H);
        }

        for (int kk = 0; kk < H / BK; ++kk) {
            // convert in registers (waits on in-flight loads here)
            uint2 ap[4], bp[4];
            #pragma unroll
            for (int i = 0; i < 4; ++i) {
                ap[i].x = cvt2(pa[i].x, pa[i].y); ap[i].y = cvt2(pa[i].z, pa[i].w);
                bp[i].x = cvt2(pb[i].x, pb[i].y); bp[i].y = cvt2(pb[i].z, pb[i].w);
            }
            __syncthreads();                 // previous iter's readers done
            #pragma unroll
            for (int i = 0; i < 4; ++i) {
                *(uint2*)&As[srow + i * 32][sc4] = ap[i];
                *(uint2*)&Bs[srow + i * 32][sc4] = bp[i];
            }
            __syncthreads();                 // writes visible
            if (kk < H / BK - 1) {           // prefetch kk+1 (flies during MFMA)
                const int h0 = (kk + 1) * BK;
                #pragma unroll
                for (int i = 0; i < 4; ++i) {
                    pa[i] = *(const float4*)(pA + (size_t)i * 32 * H + h0);
                    pb[i] = *(const float4*)(pB + (size_t)i * 32 * H + h0);
                }
            }
            bf16x8 af[4], bfr[4];
            #pragma unroll
            for (int i = 0; i < 4; ++i) af[i]  = *(const bf16x8*)&As[wr * 64 + i * 16 + c][quad * 8];
            #pragma unroll
            for (int j = 0; j < 4; ++j) bfr[j] = *(const bf16x8*)&Bs[wc * 64 + j * 16 + c][quad * 8];
            #pragma unroll
            for (int i = 0; i < 4; ++i)
                #pragma unroll
                for (int j = 0; j < 4; ++j)
                    acc[i][j] = __builtin_amdgcn_mfma_f32_16x16x32_bf16(af[i], bfr[j], acc[i][j], 0, 0, 0);
        }

        // fold this k-tile into esum (tanh epilogue)
        #pragma unroll
        for (int i = 0; i < 4; ++i)
            #pragma unroll
            for (int j = 0; j < 4; ++j) {
                const int col = kt * BN + wc * 64 + j * 16 + c;
                const float v = vS[col], uu = uS[col];
                #pragma unroll
                for (int r = 0; r < 4; ++r)
                    esum[i][r] += v * fast_tanh(uu + acc[i][j][r]);
            }
    }

    // reduce over c lanes (same quad shares the same s-row)
    #pragma unroll
    for (int i = 0; i < 4; ++i)
        #pragma unroll
        for (int r = 0; r < 4; ++r) {
            float e = esum[i][r];
            e += __shfl_xor(e, 1, 64);
            e += __shfl_xor(e, 2, 64);
            e += __shfl_xor(e, 4, 64);
            e += __shfl_xor(e, 8, 64);
            esum[i][r] = e;
        }
    __syncthreads();
    if (wc == 0 && c == 0) {
        #pragma unroll
        for (int i = 0; i < 4; ++i)
            #pragma unroll
            for (int r = 0; r < 4; ++r)
                red[wr * 64 + i * 16 + quad * 4 + r] = esum[i][r];
    }
    __syncthreads();
    if (wc == 1 && c == 0) {
        #pragma unroll
        for (int i = 0; i < 4; ++i)
            #pragma unroll
            for (int r = 0; r < 4; ++r) {
                const int row = wr * 64 + i * 16 + quad * 4 + r;
                energy[b * S + s0 + row] = red[row] + esum[i][r];
            }
    }
}

__global__ void softmax_kernel(const float* __restrict__ energy, float* __restrict__ attn) {
    int b = blockIdx.x;
    int t = threadIdx.x;              // 256
    const float* e = energy + b * S;
    float v[8];
    float m = -1e30f;
    #pragma unroll
    for (int i = 0; i < 8; ++i) { v[i] = e[t + i * 256]; m = fmaxf(m, v[i]); }
    #pragma unroll
    for (int off = 1; off < 64; off <<= 1) m = fmaxf(m, __shfl_xor(m, off, 64));
    __shared__ float redm[4], reds[4];
    if ((t & 63) == 0) redm[t >> 6] = m;
    __syncthreads();
    m = fmaxf(fmaxf(redm[0], redm[1]), fmaxf(redm[2], redm[3]));
    float s = 0.f;
    #pragma unroll
    for (int i = 0; i < 8; ++i) { v[i] = __expf(v[i] - m); s += v[i]; }
    #pragma unroll
    for (int off = 1; off < 64; off <<= 1) s += __shfl_xor(s, off, 64);
    if ((t & 63) == 0) reds[t >> 6] = s;
    __syncthreads();
    float inv = 1.0f / (reds[0] + reds[1] + reds[2] + reds[3]);
    #pragma unroll
    for (int i = 0; i < 8; ++i) attn[b * S + t + i * 256] = v[i] * inv;
}

#define CCHUNK 128
__global__ __launch_bounds__(256) void context_kernel(
        const float* __restrict__ enc, const float* __restrict__ attn,
        float* __restrict__ ctx) {
    int b  = blockIdx.x >> 4;
    int ch = blockIdx.x & 15;
    int t  = threadIdx.x;             // 256
    __shared__ float aS[CCHUNK];
    if (t < CCHUNK) aS[t] = attn[b * S + ch * CCHUNK + t];
    __syncthreads();
    const float* ebase = enc + ((size_t)(b * S + ch * CCHUNK)) * H + t;
    float c0 = 0.f, c1 = 0.f;
    #pragma unroll 8
    for (int s = 0; s < CCHUNK; ++s) {
        float a = aS[s];
        c0 += a * ebase[(size_t)s * H];
        c1 += a * ebase[(size_t)s * H + 256];
    }
    atomicAdd(&ctx[b * H + t], c0);
    atomicAdd(&ctx[b * H + t + 256], c1);
}

extern "C" void kernel_launch(void* const* d_in, const int* in_sizes, int n_in,
                              void* d_out, int out_size, void* d_ws, size_t ws_size,
                              hipStream_t stream) {
    (void)in_sizes; (void)n_in; (void)out_size; (void)ws_size;
    const float* hid = (const float*)d_in[0];
    const float* enc = (const float*)d_in[1];
    const float* Uw  = (const float*)d_in[2];
    const float* Ub  = (const float*)d_in[3];
    const float* Ww  = (const float*)d_in[4];
    const float* Wb  = (const float*)d_in[5];
    const float* Vw  = (const float*)d_in[6];
    // V_b unused: softmax shift-invariant, energy not an output.

    float* out_ctx  = (float*)d_out;          // 64*512
    float* out_attn = out_ctx + B * H;        // 64*2048
    float* energy   = (float*)d_ws;           // 64*2048 fp32
    float* u        = energy + B * S;         // 64*512 fp32

    hipMemsetAsync(d_out, 0, (size_t)B * H * sizeof(float), stream);   // ctx accum target

    u_kernel<<<dim3(H / 4, B), 256, 0, stream>>>(hid, Uw, Ub, Wb, u);
    energy_kernel<<<dim3(S / BM, B), 256, 0, stream>>>(enc, Ww, Vw, u, energy);
    softmax_kernel<<<B, 256, 0, stream>>>(energy, out_attn);
    context_kernel<<<B * (S / CCHUNK), 256, 0, stream>>>(enc, out_attn, out_ctx);
}